// Round 2
// baseline (634.181 us; speedup 1.0000x reference)
//
#include <hip/hip_runtime.h>
#include <hip/hip_bf16.h>
#include <cstdio>
#include <cstdint>

typedef __bf16 bf16_t;
typedef __bf16 bf16x8 __attribute__((ext_vector_type(8)));
typedef float f32x4 __attribute__((ext_vector_type(4)));

static constexpr int Bc = 2, Sc = 1024, HIDc = 4096;
static constexpr int NQc = 32, NKVc = 8, Dc = 128, OFFc = 1024, Tc = 2048;
static constexpr int Mrows = Bc * Sc;                 // 2048
static constexpr int NQKV = (NQc + 2 * NKVc) * Dc;    // 6144
static constexpr int NTB = Tc / 64;                   // 32 t-blocks

__device__ inline void load_lds16(const void* g, void* l) {
    __builtin_amdgcn_global_load_lds(
        (const __attribute__((address_space(1))) unsigned*)g,
        (__attribute__((address_space(3))) unsigned*)l, 16, 0, 0);
}

// ---------------- fp32 -> bf16 convert ----------------
__global__ void k_cvt(const float* __restrict__ src, bf16_t* __restrict__ dst, long n4) {
    long i = blockIdx.x * (long)blockDim.x + threadIdx.x;
    long stride = (long)gridDim.x * blockDim.x;
    const float4* s4 = (const float4*)src;
    for (; i < n4; i += stride) {
        float4 v = s4[i];
        bf16_t t[4] = {(bf16_t)v.x, (bf16_t)v.y, (bf16_t)v.z, (bf16_t)v.w};
        *(uint2*)&dst[i * 4] = *(uint2*)t;
    }
}

// ---------------- GEMM: C[M][N] = A[M][K] * B[N][K]^T (+bias) ----------------
template <bool BIAS, bool OUT_BF16>
__global__ __launch_bounds__(256) void k_gemm(const bf16_t* __restrict__ A,
                                              const bf16_t* __restrict__ Bm,
                                              const float* __restrict__ bias,
                                              void* __restrict__ Cout,
                                              int M, int N, int K) {
    __shared__ __align__(16) bf16_t As[128][32];
    __shared__ __align__(16) bf16_t Bs[128][32];
    const int tid = threadIdx.x, wid = tid >> 6, lane = tid & 63;
    const int g = lane >> 4, ln = lane & 15;
    const int wm = wid >> 1, wn = wid & 1;
    const int m0 = blockIdx.y * 128, n0 = blockIdx.x * 128;
    f32x4 acc[4][4] = {};

    for (int k0 = 0; k0 < K; k0 += 32) {
        __syncthreads();
#pragma unroll
        for (int c = 0; c < 2; ++c) {
            int row = wid * 32 + c * 16 + (lane >> 2);
            int col = (lane & 3) * 8;
            load_lds16(A + (size_t)(m0 + row) * K + k0 + col, &As[wid * 32 + c * 16][0]);
            load_lds16(Bm + (size_t)(n0 + row) * K + k0 + col, &Bs[wid * 32 + c * 16][0]);
        }
        __syncthreads();
        bf16x8 af[4], bfr[4];
#pragma unroll
        for (int i = 0; i < 4; ++i) af[i] = *(const bf16x8*)&As[wm * 64 + i * 16 + ln][g * 8];
#pragma unroll
        for (int i = 0; i < 4; ++i) bfr[i] = *(const bf16x8*)&Bs[wn * 64 + i * 16 + ln][g * 8];
#pragma unroll
        for (int i = 0; i < 4; ++i)
#pragma unroll
            for (int j = 0; j < 4; ++j)
                acc[i][j] = __builtin_amdgcn_mfma_f32_16x16x32_bf16(af[i], bfr[j], acc[i][j], 0, 0, 0);
    }

#pragma unroll
    for (int i = 0; i < 4; ++i) {
#pragma unroll
        for (int j = 0; j < 4; ++j) {
            int col = n0 + wn * 64 + j * 16 + ln;
            float bv = BIAS ? bias[col] : 0.f;
#pragma unroll
            for (int r = 0; r < 4; ++r) {
                int row = m0 + wm * 64 + i * 16 + g * 4 + r;
                float v = acc[i][j][r] + bv;
                if (OUT_BF16)
                    ((bf16_t*)Cout)[(size_t)row * N + col] = (bf16_t)v;
                else
                    ((float*)Cout)[(size_t)row * N + col] = v;
            }
        }
    }
}

// ---------------- RoPE q in place ----------------
__global__ void k_rope_q(bf16_t* __restrict__ qkv, const float* __restrict__ cosT,
                         const float* __restrict__ sinT) {
    int row = blockIdx.x;            // 0..2047 = b*1024 + s
    int s = row & 1023;
    bf16_t* src = qkv + (size_t)row * NQKV;
    for (int p = threadIdx.x; p < 2048; p += 256) {
        int j = p & 63;
        float c = cosT[s * 64 + j], sn = sinT[s * 64 + j];
        float xr = (float)src[2 * p], xi = (float)src[2 * p + 1];
        src[2 * p]     = (bf16_t)(xr * c - xi * sn);
        src[2 * p + 1] = (bf16_t)(xr * sn + xi * c);
    }
}

// ---------------- RoPE k + scatter new K/V (bf16 shadows + fp32 outs) --------
// grid (sb=16, hk=8, b=2), 256 threads. vT layout: [b][h][tb][d][64]
__global__ __launch_bounds__(256) void k_ropekv(const bf16_t* __restrict__ qkv,
                                                const float* __restrict__ cosT,
                                                const float* __restrict__ sinT,
                                                float* __restrict__ out_k,
                                                float* __restrict__ out_v,
                                                bf16_t* __restrict__ kfull,
                                                bf16_t* __restrict__ vT) {
    __shared__ __align__(16) bf16_t Vl[64][136];
    const int sb = blockIdx.x, hk = blockIdx.y, b = blockIdx.z;
    const int tid = threadIdx.x;
    const int tt = tid >> 2, dq = (tid & 3) * 32;
    const int s = sb * 64 + tt;
    const int t = OFFc + s;
    const bf16_t* krow = qkv + (size_t)(b * Sc + s) * NQKV + NQc * Dc + hk * Dc + dq;
    const bf16_t* vrow = qkv + (size_t)(b * Sc + s) * NQKV + (NQc + NKVc) * Dc + hk * Dc + dq;

    float cs[16], sn[16];
    int j0 = dq >> 1;
#pragma unroll
    for (int q4 = 0; q4 < 4; ++q4) {
        float4 cv = *(const float4*)&cosT[s * 64 + j0 + q4 * 4];
        float4 sv = *(const float4*)&sinT[s * 64 + j0 + q4 * 4];
        cs[q4 * 4] = cv.x; cs[q4 * 4 + 1] = cv.y; cs[q4 * 4 + 2] = cv.z; cs[q4 * 4 + 3] = cv.w;
        sn[q4 * 4] = sv.x; sn[q4 * 4 + 1] = sv.y; sn[q4 * 4 + 2] = sv.z; sn[q4 * 4 + 3] = sv.w;
    }

    bf16_t kb[32], vb[32];
#pragma unroll
    for (int c = 0; c < 4; ++c) {
        *(uint4*)&kb[c * 8] = *(const uint4*)&krow[c * 8];
        *(uint4*)&vb[c * 8] = *(const uint4*)&vrow[c * 8];
    }
    float ko[32], vo[32];
    bf16_t kbf[32];
#pragma unroll
    for (int jj = 0; jj < 16; ++jj) {
        float xr = (float)kb[2 * jj], xi = (float)kb[2 * jj + 1];
        ko[2 * jj]     = xr * cs[jj] - xi * sn[jj];
        ko[2 * jj + 1] = xr * sn[jj] + xi * cs[jj];
        kbf[2 * jj]     = (bf16_t)ko[2 * jj];
        kbf[2 * jj + 1] = (bf16_t)ko[2 * jj + 1];
        vo[2 * jj] = (float)vb[2 * jj];
        vo[2 * jj + 1] = (float)vb[2 * jj + 1];
    }

#pragma unroll
    for (int gg = 0; gg < 4; ++gg) {
        int hq = hk * 4 + gg;
        size_t o = ((size_t)(b * Tc + t) * NQc + hq) * Dc + dq;
#pragma unroll
        for (int c = 0; c < 4; ++c) *(uint4*)&kfull[o + c * 8] = *(uint4*)&kbf[c * 8];
#pragma unroll
        for (int c = 0; c < 8; ++c) {
            *(float4*)&out_k[o + c * 4] = *(float4*)&ko[c * 4];
            *(float4*)&out_v[o + c * 4] = *(float4*)&vo[c * 4];
        }
    }
    // LDS transpose of v -> vT subtile
#pragma unroll
    for (int c = 0; c < 4; ++c) *(uint4*)&Vl[tt][dq + c * 8] = *(uint4*)&vb[c * 8];
    __syncthreads();
#pragma unroll
    for (int i = 0; i < 4; ++i) {
        int u = i * 256 + tid;
        int d = u >> 3, cc = u & 7;
        bf16_t tmp[8];
#pragma unroll
        for (int j = 0; j < 8; ++j) tmp[j] = Vl[cc * 8 + j][d];
#pragma unroll
        for (int gg = 0; gg < 4; ++gg) {
            int hq = hk * 4 + gg;
            size_t vo2 = ((((size_t)b * NQc + hq) * NTB + (16 + sb)) * Dc + d) * 64 + cc * 8;
            *(uint4*)&vT[vo2] = *(uint4*)tmp;
        }
    }
}

// ---------------- cache copy + transpose (fp32 passthrough + bf16 shadow) ----
// grid (tb=16, h=32, b=2), 256 threads
__global__ __launch_bounds__(256) void k_cache(const float* __restrict__ kc,
                                               const float* __restrict__ vc,
                                               float* __restrict__ out_k,
                                               float* __restrict__ out_v,
                                               bf16_t* __restrict__ kfull,
                                               bf16_t* __restrict__ vT) {
    __shared__ __align__(16) bf16_t Vl[64][136];
    const int tb = blockIdx.x, h = blockIdx.y, b = blockIdx.z;
    const int tid = threadIdx.x;
    const int tt = tid >> 2, dq = (tid & 3) * 32;
    const int t = tb * 64 + tt;
    size_t src = ((size_t)(b * OFFc + t) * NQc + h) * Dc + dq;
    size_t dst = ((size_t)(b * Tc + t) * NQc + h) * Dc + dq;

    bf16_t vb[32];
#pragma unroll
    for (int c = 0; c < 8; ++c) {
        float4 kv = *(const float4*)&kc[src + c * 4];
        *(float4*)&out_k[dst + c * 4] = kv;
        bf16_t t1[4] = {(bf16_t)kv.x, (bf16_t)kv.y, (bf16_t)kv.z, (bf16_t)kv.w};
        *(uint2*)&kfull[dst + c * 4] = *(uint2*)t1;
        float4 vv = *(const float4*)&vc[src + c * 4];
        *(float4*)&out_v[dst + c * 4] = vv;
        vb[c * 4] = (bf16_t)vv.x; vb[c * 4 + 1] = (bf16_t)vv.y;
        vb[c * 4 + 2] = (bf16_t)vv.z; vb[c * 4 + 3] = (bf16_t)vv.w;
    }
#pragma unroll
    for (int c = 0; c < 4; ++c) *(uint4*)&Vl[tt][dq + c * 8] = *(uint4*)&vb[c * 8];
    __syncthreads();
#pragma unroll
    for (int i = 0; i < 4; ++i) {
        int u = i * 256 + tid;
        int d = u >> 3, cc = u & 7;
        bf16_t tmp[8];
#pragma unroll
        for (int j = 0; j < 8; ++j) tmp[j] = Vl[cc * 8 + j][d];
        size_t vo2 = ((((size_t)b * NQc + h) * NTB + tb) * Dc + d) * 64 + cc * 8;
        *(uint4*)&vT[vo2] = *(uint4*)tmp;
    }
}

// ---------------- flash attention ----------------
// QT=128, 512 threads / 8 waves (16 q-rows each), KV-tile 64.
// K tile [64][128] + V^T tile [128][64] staged via global_load_lds with
// XOR-swizzled source (16B-unit ^ row&7); P tile XOR-swizzled (8-el blocks).
__global__ __launch_bounds__(512) void k_attn(const bf16_t* __restrict__ qkv,
                                              const bf16_t* __restrict__ kfull,
                                              const bf16_t* __restrict__ vT,
                                              bf16_t* __restrict__ attn) {
    __shared__ __align__(16) bf16_t KsF[64 * 128];
    __shared__ __align__(16) bf16_t VtF[128 * 64];
    __shared__ __align__(16) bf16_t PlF[8 * 16 * 64];
    const int tid = threadIdx.x, w = tid >> 6, l = tid & 63;
    const int g = l >> 4, ln = l & 15;
    const int q0 = blockIdx.x * 128;
    const int bh = blockIdx.y, b = bh >> 5, h = bh & 31;
    const float SCALE = 0.08838834764831845f;
    const float L2E = 1.4426950408889634f;

    bf16x8 qf[4];
    {
        size_t qrow = (size_t)(b * Sc + q0 + w * 16 + ln) * NQKV + h * Dc;
#pragma unroll
        for (int dc = 0; dc < 4; ++dc) qf[dc] = *(const bf16x8*)&qkv[qrow + dc * 32 + g * 8];
    }
    f32x4 o[8] = {};
    float mrun[4] = {-1e30f, -1e30f, -1e30f, -1e30f};
    float lrun[4] = {0.f, 0.f, 0.f, 0.f};
    const int ntiles = (OFFc + q0 + 128) >> 6;
    const bf16_t* kbase = kfull + ((size_t)b * Tc * NQc + h) * Dc;
    const bf16_t* vbase = vT + ((size_t)b * NQc + h) * (size_t)NTB * Dc * 64;

    for (int t = 0; t < ntiles; ++t) {
        __syncthreads();
#pragma unroll
        for (int i = 0; i < 2; ++i) {
            int u = w * 128 + i * 64 + l;
            int kt = u >> 4, kcc = u & 15;
            load_lds16(kbase + (size_t)(t * 64 + kt) * (NQc * Dc) + ((kcc ^ (kt & 7)) * 8),
                       &KsF[(w * 128 + i * 64) * 8]);
            int vd = u >> 3, vcc = u & 7;
            load_lds16(vbase + ((size_t)t * 128 + vd) * 64 + ((vcc ^ (vd & 7)) * 8),
                       &VtF[(w * 128 + i * 64) * 8]);
        }
        __syncthreads();

        f32x4 sa[4] = {};
#pragma unroll
        for (int nf = 0; nf < 4; ++nf) {
            int kt = nf * 16 + ln;
#pragma unroll
            for (int dc = 0; dc < 4; ++dc) {
                int cu = (dc * 4 + g) ^ (kt & 7);
                bf16x8 kf8 = *(const bf16x8*)&KsF[kt * 128 + cu * 8];
                sa[nf] = __builtin_amdgcn_mfma_f32_16x16x32_bf16(qf[dc], kf8, sa[nf], 0, 0, 0);
            }
        }

        float sv[4][4];
        bool maybe = (t >= ntiles - 2);
#pragma unroll
        for (int nf = 0; nf < 4; ++nf)
#pragma unroll
            for (int r = 0; r < 4; ++r) {
                float s = sa[nf][r] * SCALE;
                if (maybe) {
                    int tg = t * 64 + nf * 16 + ln;
                    int qg = q0 + w * 16 + g * 4 + r;
                    if (tg > OFFc + qg) s = -1e30f;
                }
                sv[nf][r] = s;
            }

        float al[4];
#pragma unroll
        for (int r = 0; r < 4; ++r) {
            float tm = fmaxf(fmaxf(sv[0][r], sv[1][r]), fmaxf(sv[2][r], sv[3][r]));
#pragma unroll
            for (int msk = 1; msk < 16; msk <<= 1) tm = fmaxf(tm, __shfl_xor(tm, msk));
            float mn = fmaxf(mrun[r], tm);
            al[r] = exp2f((mrun[r] - mn) * L2E);
            mrun[r] = mn;
        }
        float ps[4] = {0.f, 0.f, 0.f, 0.f};
#pragma unroll
        for (int nf = 0; nf < 4; ++nf)
#pragma unroll
            for (int r = 0; r < 4; ++r) {
                float p = exp2f((sv[nf][r] - mrun[r]) * L2E);
                ps[r] += p;
                int q = g * 4 + r;
                PlF[(w * 16 + q) * 64 + ((nf * 16 + ln) ^ ((q & 7) << 3))] = (bf16_t)p;
            }
#pragma unroll
        for (int r = 0; r < 4; ++r) {
#pragma unroll
            for (int msk = 1; msk < 16; msk <<= 1) ps[r] += __shfl_xor(ps[r], msk);
            lrun[r] = lrun[r] * al[r] + ps[r];
        }
#pragma unroll
        for (int df = 0; df < 8; ++df) {
            f32x4 t4 = o[df];
            t4[0] *= al[0]; t4[1] *= al[1]; t4[2] *= al[2]; t4[3] *= al[3];
            o[df] = t4;
        }
#pragma unroll
        for (int kc = 0; kc < 2; ++kc) {
            bf16x8 pa = *(const bf16x8*)&PlF[(w * 16 + ln) * 64 + ((kc * 32 + g * 8) ^ ((ln & 7) << 3))];
#pragma unroll
            for (int df = 0; df < 8; ++df) {
                int d = df * 16 + ln;
                int cu = (kc * 4 + g) ^ (d & 7);
                bf16x8 bv = *(const bf16x8*)&VtF[d * 64 + cu * 8];
                o[df] = __builtin_amdgcn_mfma_f32_16x16x32_bf16(pa, bv, o[df], 0, 0, 0);
            }
        }
    }

#pragma unroll
    for (int df = 0; df < 8; ++df)
#pragma unroll
        for (int r = 0; r < 4; ++r) {
            float v = o[df][r] / lrun[r];
            size_t orow = (size_t)(b * Sc + q0 + w * 16 + g * 4 + r) * (NQc * Dc) + h * Dc + df * 16 + ln;
            attn[orow] = (bf16_t)v;
        }
}

extern "C" void kernel_launch(void* const* d_in, const int* in_sizes, int n_in,
                              void* d_out, int out_size, void* d_ws, size_t ws_size,
                              hipStream_t stream) {
    const float* x      = (const float*)d_in[0];
    const float* cosT   = (const float*)d_in[2];
    const float* sinT   = (const float*)d_in[3];
    const float* kcache = (const float*)d_in[4];
    const float* vcache = (const float*)d_in[5];
    const float* q_w    = (const float*)d_in[6];
    const float* q_b    = (const float*)d_in[7];
    const float* k_w    = (const float*)d_in[8];
    const float* k_b    = (const float*)d_in[9];
    const float* v_w    = (const float*)d_in[10];
    const float* v_b    = (const float*)d_in[11];
    const float* o_w    = (const float*)d_in[12];

    char* ws = (char*)d_ws;
    size_t off = 0;
    auto alloc = [&](size_t bytes) {
        void* p = ws + off;
        off += (bytes + 255) & ~(size_t)255;
        return p;
    };
    bf16_t* xb   = (bf16_t*)alloc((size_t)Mrows * HIDc * 2);        // reused as attn out
    bf16_t* wqkv = (bf16_t*)alloc((size_t)Bc * Tc * NQc * Dc * 4);  // reused as kfull+vT
    bf16_t* owb  = (bf16_t*)alloc((size_t)HIDc * HIDc * 2);
    bf16_t* qkv  = (bf16_t*)alloc((size_t)Mrows * NQKV * 2);
    float*  bias = (float*)alloc((size_t)NQKV * 4);
    if (off > ws_size) {
        fprintf(stderr, "WS too small: need %zu have %zu\n", off, ws_size);
        return;
    }
    bf16_t* attn  = xb;
    bf16_t* kfull = wqkv;
    bf16_t* vT    = wqkv + (size_t)Bc * Tc * NQc * Dc;

    float* out_o = (float*)d_out;
    float* out_k = out_o + (size_t)Mrows * HIDc;
    float* out_v = out_k + (size_t)Bc * Tc * NQc * Dc;

    k_cvt<<<2048, 256, 0, stream>>>(x, xb, (long)Mrows * HIDc / 4);
    k_cvt<<<2048, 256, 0, stream>>>(q_w, wqkv, (long)NQc * Dc * HIDc / 4);
    k_cvt<<<1024, 256, 0, stream>>>(k_w, wqkv + (size_t)NQc * Dc * HIDc, (long)NKVc * Dc * HIDc / 4);
    k_cvt<<<1024, 256, 0, stream>>>(v_w, wqkv + (size_t)(NQc + NKVc) * Dc * HIDc, (long)NKVc * Dc * HIDc / 4);
    k_cvt<<<2048, 256, 0, stream>>>(o_w, owb, (long)HIDc * HIDc / 4);
    (void)hipMemcpyAsync(bias, q_b, (size_t)NQc * Dc * 4, hipMemcpyDeviceToDevice, stream);
    (void)hipMemcpyAsync(bias + NQc * Dc, k_b, (size_t)NKVc * Dc * 4, hipMemcpyDeviceToDevice, stream);
    (void)hipMemcpyAsync(bias + (NQc + NKVc) * Dc, v_b, (size_t)NKVc * Dc * 4, hipMemcpyDeviceToDevice, stream);

    k_gemm<true, true><<<dim3(NQKV / 128, Mrows / 128), 256, 0, stream>>>(
        xb, wqkv, bias, qkv, Mrows, NQKV, HIDc);
    // weights in wqkv are dead after this GEMM; kfull/vT alias the region and
    // are written only by stream-ordered later kernels.
    k_rope_q<<<Mrows, 256, 0, stream>>>(qkv, cosT, sinT);
    k_ropekv<<<dim3(16, 8, 2), 256, 0, stream>>>(qkv, cosT, sinT, out_k, out_v, kfull, vT);
    k_cache<<<dim3(16, 32, 2), 256, 0, stream>>>(kcache, vcache, out_k, out_v, kfull, vT);
    k_attn<<<dim3(Sc / 128, Bc * NQc), 512, 0, stream>>>(qkv, kfull, vT, attn);
    k_gemm<false, false><<<dim3(HIDc / 128, Mrows / 128), 256, 0, stream>>>(
        attn, owb, nullptr, d_out, Mrows, HIDc, HIDc);
}